// Round 2
// baseline (68.610 us; speedup 1.0000x reference)
//
#include <hip/hip_runtime.h>

#define DIM 128
#define LEN 256
#define INV_SQRT_D 0.08838834764831845f

__global__ __launch_bounds__(256) void fused_kernel(
    const float* __restrict__ sub_feat, const float* __restrict__ mask,
    const float* __restrict__ Wq, const float* __restrict__ bq,
    const float* __restrict__ Wk, const float* __restrict__ bk,
    const int* __restrict__ sub_index, float* __restrict__ out)
{
    const int b    = blockIdx.x;
    const int t    = threadIdx.x;
    const int lane = t & 63;
    const int wave = t >> 6;

    __shared__ int   idxs[LEN];
    __shared__ float g0[DIM];
    __shared__ float q0s[DIM];
    __shared__ float tmp2[2][DIM];
    __shared__ float vv[DIM];
    __shared__ float sc[LEN];
    __shared__ float red[4];
    __shared__ float q0bk;
    __shared__ float op[4][DIM];

    // ---- indices for this batch ----
    idxs[t] = sub_index[b * LEN + t];
    __syncthreads();

    // ---- g0 = gathered[b, 0, :] ----
    const int r0 = idxs[0];
    if (t < DIM) g0[t] = sub_feat[(size_t)r0 * DIM + t];
    __syncthreads();

    // ---- q0[d] = sum_e g0[e] * Wq[e,d] + bq[d] ----
    {
        int d = t & (DIM - 1);
        int h = t >> 7;
        float acc = 0.f;
        #pragma unroll 8
        for (int e = h * 64; e < h * 64 + 64; ++e)
            acc = fmaf(g0[e], Wq[e * DIM + d], acc);
        tmp2[h][d] = acc;
    }
    __syncthreads();
    if (t < DIM) q0s[t] = tmp2[0][t] + tmp2[1][t] + bq[t];
    __syncthreads();

    // ---- q0 · bk (scalar) ----
    {
        float p = (t < DIM) ? q0s[t] * bk[t] : 0.f;
        #pragma unroll
        for (int o = 32; o > 0; o >>= 1) p += __shfl_down(p, o);
        if (lane == 0) red[wave] = p;
        __syncthreads();
        if (t == 0) q0bk = red[0] + red[1] + red[2] + red[3];
        __syncthreads();
    }

    // ---- v[e] = Wk[e,:] · q0  (row-contiguous float4 loads) ----
    {
        int e = t & (DIM - 1);
        int h = t >> 7;
        const float4* row = reinterpret_cast<const float4*>(Wk + e * DIM + h * 64);
        float acc = 0.f;
        #pragma unroll
        for (int i = 0; i < 16; ++i) {
            float4 u = row[i];
            const float* q = &q0s[h * 64 + i * 4];
            acc += u.x * q[0] + u.y * q[1] + u.z * q[2] + u.w * q[3];
        }
        tmp2[h][e] = acc;
    }
    __syncthreads();
    if (t < DIM) vv[t] = tmp2[0][t] + tmp2[1][t];
    __syncthreads();

    // ---- scores[j] = (g_j · v + q0·bk) * inv_sqrt_d + (1-mask)*-1e4 ----
    float s;
    {
        const float4* row = reinterpret_cast<const float4*>(sub_feat + (size_t)idxs[t] * DIM);
        float acc = 0.f;
        #pragma unroll
        for (int i = 0; i < 32; ++i) {
            float4 u = row[i];
            const float* q = &vv[i * 4];
            acc += u.x * q[0] + u.y * q[1] + u.z * q[2] + u.w * q[3];
        }
        float mk = mask[b * LEN + t];
        s = (acc + q0bk) * INV_SQRT_D + (1.f - mk) * (-10000.f);
    }

    // ---- softmax over 256 scores ----
    float pm = s;
    #pragma unroll
    for (int o = 32; o > 0; o >>= 1) pm = fmaxf(pm, __shfl_xor(pm, o));
    if (lane == 0) red[wave] = pm;
    __syncthreads();
    pm = fmaxf(fmaxf(red[0], red[1]), fmaxf(red[2], red[3]));
    float ev = __expf(s - pm);
    float ps = ev;
    #pragma unroll
    for (int o = 32; o > 0; o >>= 1) ps += __shfl_xor(ps, o);
    __syncthreads();              // red[] reuse
    if (lane == 0) red[wave] = ps;
    __syncthreads();
    ps = red[0] + red[1] + red[2] + red[3];
    sc[t] = ev / ps;
    __syncthreads();

    // ---- out[b,d] = sum_j sc[j] * gathered[j][d]; wave w owns 64 j's, lanes cover 128 d via float2 ----
    {
        float ax = 0.f, ay = 0.f;
        const int jbase = wave * 64;
        for (int j = jbase; j < jbase + 64; ++j) {
            float2 u = reinterpret_cast<const float2*>(sub_feat + (size_t)idxs[j] * DIM)[lane];
            float p = sc[j];
            ax = fmaf(p, u.x, ax);
            ay = fmaf(p, u.y, ay);
        }
        op[wave][2 * lane]     = ax;
        op[wave][2 * lane + 1] = ay;
    }
    __syncthreads();
    if (t < DIM) {
        out[b * DIM + t] = op[0][t] + op[1][t] + op[2][t] + op[3][t];
    }
}

extern "C" void kernel_launch(void* const* d_in, const int* in_sizes, int n_in,
                              void* d_out, int out_size, void* d_ws, size_t ws_size,
                              hipStream_t stream) {
    const float* sub_feat  = (const float*)d_in[0];
    const float* mask      = (const float*)d_in[1];
    const float* Wq        = (const float*)d_in[2];
    const float* bq        = (const float*)d_in[3];
    const float* Wk        = (const float*)d_in[4];
    const float* bk        = (const float*)d_in[5];
    const int*   sub_index = (const int*)d_in[6];
    float* outp = (float*)d_out;

    const int B = in_sizes[6] / LEN;   // 2048
    fused_kernel<<<dim3(B), dim3(256), 0, stream>>>(
        sub_feat, mask, Wq, bq, Wk, bk, sub_index, outp);
}